// Round 14
// baseline (599.005 us; speedup 1.0000x reference)
//
#include <hip/hip_runtime.h>

typedef short short8 __attribute__((ext_vector_type(8)));
typedef float floatx16 __attribute__((ext_vector_type(16)));

#define B_    4
#define NPTS  8192          // N == M == 8192
#define IS    16            // i-splits (512 src per block)
#define JS    32            // j-splits (256 dst per block)
#define ITB   512
#define JTB   256
#define NT    4             // i-tiles (32 i) per wave -> 128 i/wave
#define NJT   8             // j-tiles (32 j) per block
#define TOT   (B_ * NPTS)   // 32768

// LDS offsets in short8 units (typed => 16B-aligned). A=dst (256 pts),
// B=src (512 pts); seg0/seg1 = k0..7 / k8..15.
#define A0OFF 0
#define A1OFF 260
#define B0OFF 524
#define B1OFF 1040
#define LDS8N 1552          // 24,832 B -> 6 blocks/CU (R11's occupancy point)

// ws: slots uint32[2*TOT] = 256 KiB, memset 0xFF. Monotone float->uint map.
//
// HAZARD RULE (R10/R12/R13 post-mortem): NEVER read MFMA results via inline
// asm — MFMA->VALU-read is a software-managed hazard; compiler-emitted
// v_min handles it (and still forms v_min3), raw asm does not. All folds
// below are fminf only. R9/R11 (fminf): absmax 0.0; R10/R12/R13 (asm): fail.

__device__ __forceinline__ unsigned short bf16h(float v) {
  unsigned u = __float_as_uint(v);
  return (unsigned short)((u + 0x7FFFu + ((u >> 16) & 1u)) >> 16);   // RNE
}
__device__ __forceinline__ void bf16split(float v, unsigned short& h, unsigned short& l) {
  h = bf16h(v);
  l = bf16h(v - __uint_as_float((unsigned)h << 16));
}

// K-slot payload (16 slots, all real — 32x32x16 K=16 exactly, zero waste):
//   A (dst j): k0..7  [axh axh axl axl  ayh ayh ayl ayl]      a = -2g
//              k8..15 [azh azh azl azl  wh  wl  1   1 ]       w = ||g||^2
//   B (src i): k0..7  [pxh pxl pxh pxl  pyh pyl pyh pyl]
//              k8..15 [pzh pzl pzh pzl  1   1   qh  ql]       q = ||p||^2
// Sum_k = -2<g,p> + ||g||^2 + ||p||^2  (payload R9/R11-verified, absmax 0.0)
__device__ __forceinline__ void pack_dst(const float* g, short8& s0, short8& s1) {
  const float x = g[0], y = g[1], z = g[2];
  const float w = fmaf(x, x, fmaf(y, y, z * z));
  unsigned short xh, xl, yh, yl, zh, zl, wh, wl;
  bf16split(-2.f * x, xh, xl); bf16split(-2.f * y, yh, yl);
  bf16split(-2.f * z, zh, zl); bf16split(w, wh, wl);
  s0 = (short8){(short)xh,(short)xh,(short)xl,(short)xl,
                (short)yh,(short)yh,(short)yl,(short)yl};
  s1 = (short8){(short)zh,(short)zh,(short)zl,(short)zl,
                (short)wh,(short)wl,(short)0x3F80,(short)0x3F80};
}
__device__ __forceinline__ void pack_src(const float* p, short8& s0, short8& s1) {
  const float x = p[0], y = p[1], z = p[2];
  const float qq = fmaf(x, x, fmaf(y, y, z * z));
  unsigned short xh, xl, yh, yl, zh, zl, qh, ql;
  bf16split(x, xh, xl); bf16split(y, yh, yl);
  bf16split(z, zh, zl); bf16split(qq, qh, ql);
  s0 = (short8){(short)xh,(short)xl,(short)xh,(short)xl,
                (short)yh,(short)yl,(short)yh,(short)yl};
  s1 = (short8){(short)zh,(short)zl,(short)zh,(short)zl,
                (short)0x3F80,(short)0x3F80,(short)qh,(short)ql};
}

// grid (IS, JS, 2*B_) = (16,32,8) = 4096 blocks, 256 thr (4 waves).
// Block: 512 i x 256 j. Wave w: i in [w*128, w*128+128), all 256 j.
// 32x32x16 fragment map (clean retest of R10's hypothesis): lane half
// h=lane>>5 holds k=h*8+elem; A m=lane&31 (j), B n=lane&31 (i). C/D: lane
// col i=n, 16 regs + shfl_xor(32) cover all 32 j — row order irrelevant.
__global__ __launch_bounds__(256, 4) void mfma_pass_kernel(
    const float* __restrict__ pred, const float* __restrict__ gt,
    unsigned* __restrict__ slots) {
  __shared__ short8 lds8[LDS8N];

  const int zb  = blockIdx.z;
  const int dir = zb >> 2;
  const int b   = zb & 3;
  const float* src = dir ? gt   : pred;   // i-cloud (min FOR these)
  const float* dst = dir ? pred : gt;     // j-cloud (min OVER these)

  const int tid   = threadIdx.x;
  const int lane  = tid & 63;
  const int w     = tid >> 6;
  const int jbase = blockIdx.y * JTB;
  const int ibase = blockIdx.x * ITB;

  // Stage: 256 dst (1/thread) + 512 src (2/thread).
  {
    short8 s0, s1;
    pack_dst(dst + ((size_t)b * NPTS + jbase + tid) * 3, s0, s1);
    lds8[A0OFF + tid] = s0;
    lds8[A1OFF + tid] = s1;
#pragma unroll
    for (int r = 0; r < 2; ++r) {
      const int pt = tid + r * 256;
      pack_src(src + ((size_t)b * NPTS + ibase + pt) * 3, s0, s1);
      lds8[B0OFF + pt] = s0;
      lds8[B1OFF + pt] = s1;
    }
  }
  __syncthreads();

  const int h = lane >> 5;     // k-half: k = h*8 + elem
  const int n = lane & 31;     // point index within 32-tile (A: j, B: i)
  const int bseg = h ? B1OFF : B0OFF;
  const int aseg = h ? A1OFF : A0OFF;

  short8 bf[NT];
  float  m[NT];
#pragma unroll
  for (int t = 0; t < NT; ++t) {
    bf[t] = lds8[bseg + w * 128 + t * 32 + n];
    m[t] = 1e30f;
  }

  const floatx16 zero16 = {0.f,0.f,0.f,0.f, 0.f,0.f,0.f,0.f,
                           0.f,0.f,0.f,0.f, 0.f,0.f,0.f,0.f};
  short8 af = lds8[aseg + n];              // jt = 0
  for (int jt = 0; jt < NJT; ++jt) {
    const int jn = (jt + 1 < NJT) ? (jt + 1) : 0;
    const short8 afn = lds8[aseg + jn * 32 + n];   // prefetch next j-tile
    floatx16 d[NT];
#pragma unroll
    for (int t = 0; t < NT; ++t)   // 4 independent MFMAs, back-to-back issue
      d[t] = __builtin_amdgcn_mfma_f32_32x32x16_bf16(af, bf[t], zero16, 0, 0, 0);
#pragma unroll
    for (int t = 0; t < NT; ++t) { // fold after — fminf ONLY (hazard rule)
      float r0 = fminf(fminf(d[t][0],  d[t][1]),  fminf(d[t][2],  d[t][3]));
      float r1 = fminf(fminf(d[t][4],  d[t][5]),  fminf(d[t][6],  d[t][7]));
      float r2 = fminf(fminf(d[t][8],  d[t][9]),  fminf(d[t][10], d[t][11]));
      float r3 = fminf(fminf(d[t][12], d[t][13]), fminf(d[t][14], d[t][15]));
      m[t] = fminf(m[t], fminf(fminf(r0, r1), fminf(r2, r3)));
    }
    af = afn;
  }

  // Lanes n and n+32 share col i=n: one shfl fold, one atomicMin per (i,block).
#pragma unroll
  for (int t = 0; t < NT; ++t) {
    const float v = fminf(m[t], __shfl_xor(m[t], 32));
    if (lane < 32) {
      const int gi = ibase + w * 128 + t * 32 + n;
      const int bi = __float_as_int(v);
      const unsigned u = (unsigned)bi ^ (unsigned)((bi >> 31) | 0x80000000);
      atomicMin(&slots[(size_t)(dir * B_ + b) * NPTS + gi], u);
    }
  }
}

// Sweep 2*TOT slots, decode, reduce, one atomic per block.  (R5-proven)
__global__ __launch_bounds__(256) void pass2_kernel(
    const unsigned* __restrict__ slots, float* __restrict__ out) {
  const int gid = blockIdx.x * 256 + threadIdx.x;   // 8192 threads
  float s = 0.f;
#pragma unroll
  for (int k = 0; k < 8; ++k) {
    const unsigned u = slots[gid + k * 8192];
    const int bi = (u & 0x80000000u) ? (int)(u ^ 0x80000000u) : (int)~u;
    s += __int_as_float(bi);
  }
  __shared__ float red[256];
  const int tid = threadIdx.x;
  red[tid] = s;
  __syncthreads();
  for (int st = 128; st > 0; st >>= 1) {
    if (tid < st) red[tid] += red[tid + st];
    __syncthreads();
  }
  if (tid == 0) atomicAdd(out, red[0] * (1.0f / TOT));
}

extern "C" void kernel_launch(void* const* d_in, const int* in_sizes, int n_in,
                              void* d_out, int out_size, void* d_ws, size_t ws_size,
                              hipStream_t stream) {
  const float* pred = (const float*)d_in[0];
  const float* gt   = (const float*)d_in[1];
  unsigned* slots = (unsigned*)d_ws;
  float* out = (float*)d_out;

  hipMemsetAsync(slots, 0xFF, (size_t)2 * TOT * sizeof(unsigned), stream);
  hipMemsetAsync(out, 0, out_size * sizeof(float), stream);

  dim3 g(IS, JS, 2 * B_);   // 4096 blocks
  mfma_pass_kernel<<<g, 256, 0, stream>>>(pred, gt, slots);

  pass2_kernel<<<(2 * TOT) / (256 * 8), 256, 0, stream>>>(slots, out);
}